// Round 4
// baseline (1668.995 us; speedup 1.0000x reference)
//
#include <hip/hip_runtime.h>

typedef __attribute__((ext_vector_type(4))) float f32x4;
typedef __attribute__((ext_vector_type(8))) __bf16 bf16x8;

#define NROWS   32768
#define KDIM    768
#define NDIM    2048
#define HDIM    512
#define LDS_BYTES 135168   // [0,128K) gates bf16[32][2048] (A-tile 96K unions here), [128K,132K) reduce scratch

__device__ __forceinline__ unsigned short f2bf(float f) {
  unsigned int u = __builtin_bit_cast(unsigned int, f);
  u += 0x7fffu + ((u >> 16) & 1u);          // RNE
  return (unsigned short)(u >> 16);
}
__device__ __forceinline__ float2 bf2x2(const unsigned short* p) {
  unsigned int u = *reinterpret_cast<const unsigned int*>(p);
  float2 r;
  r.x = __builtin_bit_cast(float, u << 16);
  r.y = __builtin_bit_cast(float, u & 0xffff0000u);
  return r;
}

// ---- kernel 0: pack W fp32 [768][2048] -> bf16 fragment-order buffer ----
// element index = ((nb*24 + kb)*64 + lane)*8 + j  holds  W[kb*32 + (lane>>4)*8 + j][nb*16 + (lane&15)]
__global__ void pack_w_kernel(const float* __restrict__ W, unsigned short* __restrict__ Wp) {
  int t = blockIdx.x * 256 + threadIdx.x;      // 0 .. 196607
  int lane = t & 63;
  int frag = t >> 6;                           // nb*24 + kb
  int kb = frag % 24;
  int nb = frag / 24;
  int krow = kb * 32 + (lane >> 4) * 8;
  int col  = nb * 16 + (lane & 15);
  unsigned int v[8];
  #pragma unroll
  for (int j = 0; j < 8; j++)
    v[j] = f2bf(W[(size_t)(krow + j) * NDIM + col]);
  uint4 pk;
  pk.x = v[0] | (v[1] << 16);
  pk.y = v[2] | (v[3] << 16);
  pk.z = v[4] | (v[5] << 16);
  pk.w = v[6] | (v[7] << 16);
  *reinterpret_cast<uint4*>(Wp + (size_t)t * 8) = pk;
}

// ---- main fused kernel: GEMM + LayerNorm + gates + cell update ----
__global__ __launch_bounds__(1024) void lstm_main(
    const float* __restrict__ x, const float* __restrict__ hprev,
    const float* __restrict__ cprev, const unsigned short* __restrict__ Wp,
    const float* __restrict__ bias, const float* __restrict__ gamma,
    const float* __restrict__ beta, float* __restrict__ out)
{
  extern __shared__ char smem[];
  float* red = reinterpret_cast<float*>(smem + 131072);   // [64 rows][8 waves][2]

  const int tid  = threadIdx.x;
  const int lane = tid & 63;
  const int wid  = tid >> 6;
  const int mw = wid >> 3;                 // 0..1  (row half)
  const int nw = wid & 7;                  // 0..7  (256-col slice)
  const int rowbase = blockIdx.x * 64;

  // ---- stage A = [x | h_prev] rows into LDS as bf16, XOR-swizzled ----
  // 64 rows x 768 cols, 8-elem chunks: 96 chunks/row, 6144 total, 6/thread
  #pragma unroll
  for (int i = 0; i < 6; i++) {
    int chunk = tid + i * 1024;
    int r  = chunk / 96;
    int kc = chunk % 96;
    int k  = kc * 8;
    int grow = rowbase + r;
    const float* src = (k < 256) ? (x + (size_t)grow * 256 + k)
                                 : (hprev + (size_t)grow * 512 + (k - 256));
    float4 lo = *reinterpret_cast<const float4*>(src);
    float4 hi = *reinterpret_cast<const float4*>(src + 4);
    uint4 pk;
    pk.x = (unsigned)f2bf(lo.x) | ((unsigned)f2bf(lo.y) << 16);
    pk.y = (unsigned)f2bf(lo.z) | ((unsigned)f2bf(lo.w) << 16);
    pk.z = (unsigned)f2bf(hi.x) | ((unsigned)f2bf(hi.y) << 16);
    pk.w = (unsigned)f2bf(hi.z) | ((unsigned)f2bf(hi.w) << 16);
    int boff = r * 1536 + ((k * 2) ^ ((r & 7) << 4));
    *reinterpret_cast<uint4*>(smem + boff) = pk;
  }
  __syncthreads();

  // ---- K-loop: acc[2 mfrag][16 nfrag], each wave = 32 rows x 256 cols ----
  f32x4 acc[2][16];
  #pragma unroll
  for (int mf = 0; mf < 2; mf++)
    #pragma unroll
    for (int t = 0; t < 16; t++)
      acc[mf][t] = (f32x4){0.f, 0.f, 0.f, 0.f};

  const int arow0 = mw * 32 + (lane & 15);
  const int kgrp  = lane >> 4;
  const int xorm  = (arow0 & 7) << 4;

  for (int kb = 0; kb < 24; kb++) {
    int cb   = kb * 64 + kgrp * 16;
    int off0 = arow0 * 1536 + (cb ^ xorm);
    bf16x8 a0 = *reinterpret_cast<const bf16x8*>(smem + off0);
    bf16x8 a1 = *reinterpret_cast<const bf16x8*>(smem + off0 + 16 * 1536);
    const unsigned short* wp = Wp + ((size_t)(nw * 16 * 24 + kb) * 64 + lane) * 8;
    #pragma unroll
    for (int t = 0; t < 16; t++) {
      bf16x8 bt = *reinterpret_cast<const bf16x8*>(wp + (size_t)t * 24 * 64 * 8);
      acc[0][t] = __builtin_amdgcn_mfma_f32_16x16x32_bf16(a0, bt, acc[0][t], 0, 0, 0);
      acc[1][t] = __builtin_amdgcn_mfma_f32_16x16x32_bf16(a1, bt, acc[1][t], 0, 0, 0);
    }
  }

  // ---- bias + LN statistics (col = nw*256 + t*16 + (lane&15), row = mw*32+mf*16+(lane>>4)*4+r) ----
  const int colb = nw * 256 + (lane & 15);
  float bv[16], gv[16], btv[16];
  #pragma unroll
  for (int t = 0; t < 16; t++) {
    int c = colb + t * 16;
    bv[t] = bias[c]; gv[t] = gamma[c]; btv[t] = beta[c];
  }
  float s[2][4], q[2][4];
  #pragma unroll
  for (int mf = 0; mf < 2; mf++)
    #pragma unroll
    for (int r = 0; r < 4; r++) { s[mf][r] = 0.f; q[mf][r] = 0.f; }
  #pragma unroll
  for (int mf = 0; mf < 2; mf++)
    #pragma unroll
    for (int t = 0; t < 16; t++)
      #pragma unroll
      for (int r = 0; r < 4; r++) {
        float z = acc[mf][t][r] + bv[t];
        acc[mf][t][r] = z;
        s[mf][r] += z;
        q[mf][r] += z * z;
      }
  #pragma unroll
  for (int m = 1; m <= 8; m <<= 1) {
    #pragma unroll
    for (int mf = 0; mf < 2; mf++)
      #pragma unroll
      for (int r = 0; r < 4; r++) {
        s[mf][r] += __shfl_xor(s[mf][r], m);
        q[mf][r] += __shfl_xor(q[mf][r], m);
      }
  }
  if ((lane & 15) == 0) {
    int g = lane >> 4;
    #pragma unroll
    for (int mf = 0; mf < 2; mf++)
      #pragma unroll
      for (int r = 0; r < 4; r++) {
        int row64 = mw * 32 + mf * 16 + g * 4 + r;
        red[(row64 * 8 + nw) * 2 + 0] = s[mf][r];
        red[(row64 * 8 + nw) * 2 + 1] = q[mf][r];
      }
  }
  __syncthreads();
  float mu[2][4], rs[2][4];
  #pragma unroll
  for (int mf = 0; mf < 2; mf++)
    #pragma unroll
    for (int r = 0; r < 4; r++) {
      int row64 = mw * 32 + mf * 16 + (lane >> 4) * 4 + r;
      float ts = 0.f, tq = 0.f;
      #pragma unroll
      for (int w = 0; w < 8; w++) {
        ts += red[(row64 * 8 + w) * 2 + 0];
        tq += red[(row64 * 8 + w) * 2 + 1];
      }
      float m_ = ts * (1.0f / 2048.0f);
      float v_ = tq * (1.0f / 2048.0f) - m_ * m_;
      mu[mf][r] = m_;
      rs[mf][r] = rsqrtf(v_ + 1e-5f);
    }

  // ---- gate exchange + cell update, two 32-row phases ----
  unsigned short* gates = reinterpret_cast<unsigned short*>(smem);
  const int gsel = nw >> 1;                // 0:i 1:f 2:g 3:o
  for (int p = 0; p < 2; p++) {
    __syncthreads();
    if (mw == p) {
      #pragma unroll
      for (int mf = 0; mf < 2; mf++)
        #pragma unroll
        for (int t = 0; t < 16; t++)
          #pragma unroll
          for (int r = 0; r < 4; r++) {
            float zn = (acc[mf][t][r] - mu[mf][r]) * rs[mf][r] * gv[t] + btv[t];
            float a;
            if (gsel == 2) a = tanhf(zn);
            else           a = 1.0f / (1.0f + __expf(-zn));
            int lrow = mf * 16 + (lane >> 4) * 4 + r;
            gates[lrow * 2048 + colb + t * 16] = f2bf(a);
          }
    }
    __syncthreads();
    #pragma unroll
    for (int j = 0; j < 8; j++) {
      int idx  = tid + j * 1024;           // 0..8191 (col-pairs)
      int col  = (idx & 255) * 2;
      int lr   = idx >> 8;                 // 0..31
      int grow = rowbase + p * 32 + lr;
      float2 iv = bf2x2(gates + lr * 2048 + col);
      float2 fv = bf2x2(gates + lr * 2048 + 512 + col);
      float2 gg = bf2x2(gates + lr * 2048 + 1024 + col);
      float2 ov = bf2x2(gates + lr * 2048 + 1536 + col);
      float2 cp = *reinterpret_cast<const float2*>(cprev + (size_t)grow * 512 + col);
      float2 cn, hn;
      cn.x = fv.x * cp.x + iv.x * gg.x;
      cn.y = fv.y * cp.y + iv.y * gg.y;
      hn.x = ov.x * tanhf(cn.x);
      hn.y = ov.y * tanhf(cn.y);
      *reinterpret_cast<float2*>(out + (size_t)grow * 512 + col) = hn;
      *reinterpret_cast<float2*>(out + (size_t)NROWS * 512 + (size_t)grow * 512 + col) = cn;
    }
  }
}

extern "C" void kernel_launch(void* const* d_in, const int* in_sizes, int n_in,
                              void* d_out, int out_size, void* d_ws, size_t ws_size,
                              hipStream_t stream) {
  (void)in_sizes; (void)n_in; (void)out_size; (void)ws_size;
  const float* x     = (const float*)d_in[0];
  const float* h     = (const float*)d_in[1];
  const float* c     = (const float*)d_in[2];
  const float* W     = (const float*)d_in[3];
  const float* b     = (const float*)d_in[4];
  const float* gamma = (const float*)d_in[5];
  const float* beta  = (const float*)d_in[6];
  float* out = (float*)d_out;
  unsigned short* Wp = (unsigned short*)d_ws;   // 3 MB packed bf16 W

  hipFuncSetAttribute((const void*)lstm_main,
                      hipFuncAttributeMaxDynamicSharedMemorySize, LDS_BYTES);

  hipLaunchKernelGGL(pack_w_kernel, dim3(768), dim3(256), 0, stream, W, Wp);
  hipLaunchKernelGGL(lstm_main, dim3(512), dim3(1024), LDS_BYTES, stream,
                     x, h, c, Wp, b, gamma, beta, out);
}

// Round 5
// 609.904 us; speedup vs baseline: 2.7365x; 2.7365x over previous
//
#include <hip/hip_runtime.h>

typedef __attribute__((ext_vector_type(4))) float f32x4;
typedef __attribute__((ext_vector_type(8))) __bf16 bf16x8;

#define NROWS   32768
#define KDIM    768
#define NDIM    2048
#define HDIM    512
// [0,128K) gates bf16[32][2048]  (A-tile 48K unions at [0,48K), dead after K-loop)
// [128K,130K) reduce scratch [32 rows][8 waves][2]
#define LDS_BYTES 133120

__device__ __forceinline__ unsigned short f2bf(float f) {
  unsigned int u = __builtin_bit_cast(unsigned int, f);
  u += 0x7fffu + ((u >> 16) & 1u);          // RNE
  return (unsigned short)(u >> 16);
}
__device__ __forceinline__ float2 bf2x2(const unsigned short* p) {
  unsigned int u = *reinterpret_cast<const unsigned int*>(p);
  float2 r;
  r.x = __builtin_bit_cast(float, u << 16);
  r.y = __builtin_bit_cast(float, u & 0xffff0000u);
  return r;
}

// ---- kernel 0: pack W fp32 [768][2048] -> bf16 fragment-order buffer ----
// element index = ((nb*24 + kb)*64 + lane)*8 + j  holds  W[kb*32 + (lane>>4)*8 + j][nb*16 + (lane&15)]
__global__ void pack_w_kernel(const float* __restrict__ W, unsigned short* __restrict__ Wp) {
  int t = blockIdx.x * 256 + threadIdx.x;      // 0 .. 196607
  int lane = t & 63;
  int frag = t >> 6;                           // nb*24 + kb
  int kb = frag % 24;
  int nb = frag / 24;
  int krow = kb * 32 + (lane >> 4) * 8;
  int col  = nb * 16 + (lane & 15);
  unsigned int v[8];
  #pragma unroll
  for (int j = 0; j < 8; j++)
    v[j] = f2bf(W[(size_t)(krow + j) * NDIM + col]);
  uint4 pk;
  pk.x = v[0] | (v[1] << 16);
  pk.y = v[2] | (v[3] << 16);
  pk.z = v[4] | (v[5] << 16);
  pk.w = v[6] | (v[7] << 16);
  *reinterpret_cast<uint4*>(Wp + (size_t)t * 8) = pk;
}

// ---- main fused kernel: GEMM + LayerNorm + gates + cell update ----
// 512 threads = 8 waves = 2 waves/SIMD -> 256-reg/wave budget (no spill).
// Block: 32 rows x 2048 cols. Wave: 32 rows x 256 cols (nw = wid).
__global__ __launch_bounds__(512, 2) void lstm_main(
    const float* __restrict__ x, const float* __restrict__ hprev,
    const float* __restrict__ cprev, const unsigned short* __restrict__ Wp,
    const float* __restrict__ bias, const float* __restrict__ gamma,
    const float* __restrict__ beta, float* __restrict__ out)
{
  extern __shared__ char smem[];
  float* red = reinterpret_cast<float*>(smem + 131072);   // [32 rows][8 waves][2]

  const int tid  = threadIdx.x;
  const int lane = tid & 63;
  const int nw   = tid >> 6;               // 0..7  (256-col slice)
  const int rowbase = blockIdx.x * 32;

  // ---- stage A = [x | h_prev] rows into LDS as bf16, XOR-swizzled ----
  // 32 rows x 768 cols, 8-elem chunks: 96/row, 3072 total, 6/thread
  #pragma unroll
  for (int i = 0; i < 6; i++) {
    int chunk = tid + i * 512;
    int r  = chunk / 96;
    int kc = chunk % 96;
    int k  = kc * 8;
    int grow = rowbase + r;
    const float* src = (k < 256) ? (x + (size_t)grow * 256 + k)
                                 : (hprev + (size_t)grow * 512 + (k - 256));
    float4 lo = *reinterpret_cast<const float4*>(src);
    float4 hi = *reinterpret_cast<const float4*>(src + 4);
    uint4 pk;
    pk.x = (unsigned)f2bf(lo.x) | ((unsigned)f2bf(lo.y) << 16);
    pk.y = (unsigned)f2bf(lo.z) | ((unsigned)f2bf(lo.w) << 16);
    pk.z = (unsigned)f2bf(hi.x) | ((unsigned)f2bf(hi.y) << 16);
    pk.w = (unsigned)f2bf(hi.z) | ((unsigned)f2bf(hi.w) << 16);
    int boff = r * 1536 + ((k * 2) ^ ((r & 7) << 4));
    *reinterpret_cast<uint4*>(smem + boff) = pk;
  }
  __syncthreads();

  // ---- K-loop: acc[2 mfrag][16 nfrag]; mf0 = rows 0-15, mf1 = rows 16-31 ----
  f32x4 acc[2][16];
  #pragma unroll
  for (int mf = 0; mf < 2; mf++)
    #pragma unroll
    for (int t = 0; t < 16; t++)
      acc[mf][t] = (f32x4){0.f, 0.f, 0.f, 0.f};

  const int arow0 = lane & 15;
  const int kgrp  = lane >> 4;
  const int xorm  = (arow0 & 7) << 4;

  for (int kb = 0; kb < 24; kb++) {
    int cb   = kb * 64 + kgrp * 16;
    int off0 = arow0 * 1536 + (cb ^ xorm);
    bf16x8 a0 = *reinterpret_cast<const bf16x8*>(smem + off0);
    bf16x8 a1 = *reinterpret_cast<const bf16x8*>(smem + off0 + 16 * 1536);
    const unsigned short* wp = Wp + ((size_t)(nw * 16 * 24 + kb) * 64 + lane) * 8;
    #pragma unroll
    for (int t = 0; t < 16; t++) {
      bf16x8 bt = *reinterpret_cast<const bf16x8*>(wp + (size_t)t * 24 * 64 * 8);
      acc[0][t] = __builtin_amdgcn_mfma_f32_16x16x32_bf16(a0, bt, acc[0][t], 0, 0, 0);
      acc[1][t] = __builtin_amdgcn_mfma_f32_16x16x32_bf16(a1, bt, acc[1][t], 0, 0, 0);
    }
  }

  // ---- bias + LN stats (col = nw*256 + t*16 + (lane&15), row = mf*16+(lane>>4)*4+r) ----
  const int colb = nw * 256 + (lane & 15);
  float s[2][4], q[2][4];
  #pragma unroll
  for (int mf = 0; mf < 2; mf++)
    #pragma unroll
    for (int r = 0; r < 4; r++) { s[mf][r] = 0.f; q[mf][r] = 0.f; }
  #pragma unroll
  for (int t = 0; t < 16; t++) {
    float bv = bias[colb + t * 16];          // transient load (keeps VGPR pressure low)
    #pragma unroll
    for (int mf = 0; mf < 2; mf++)
      #pragma unroll
      for (int r = 0; r < 4; r++) {
        float z = acc[mf][t][r] + bv;
        acc[mf][t][r] = z;
        s[mf][r] += z;
        q[mf][r] += z * z;
      }
  }
  #pragma unroll
  for (int m = 1; m <= 8; m <<= 1) {
    #pragma unroll
    for (int mf = 0; mf < 2; mf++)
      #pragma unroll
      for (int r = 0; r < 4; r++) {
        s[mf][r] += __shfl_xor(s[mf][r], m);
        q[mf][r] += __shfl_xor(q[mf][r], m);
      }
  }
  if ((lane & 15) == 0) {
    int g = lane >> 4;
    #pragma unroll
    for (int mf = 0; mf < 2; mf++)
      #pragma unroll
      for (int r = 0; r < 4; r++) {
        int row32 = mf * 16 + g * 4 + r;
        red[(row32 * 8 + nw) * 2 + 0] = s[mf][r];
        red[(row32 * 8 + nw) * 2 + 1] = q[mf][r];
      }
  }
  __syncthreads();
  float mu[2][4], rs[2][4];
  #pragma unroll
  for (int mf = 0; mf < 2; mf++)
    #pragma unroll
    for (int r = 0; r < 4; r++) {
      int row32 = mf * 16 + (lane >> 4) * 4 + r;
      float ts = 0.f, tq = 0.f;
      #pragma unroll
      for (int w = 0; w < 8; w++) {
        ts += red[(row32 * 8 + w) * 2 + 0];
        tq += red[(row32 * 8 + w) * 2 + 1];
      }
      float m_ = ts * (1.0f / 2048.0f);
      float v_ = tq * (1.0f / 2048.0f) - m_ * m_;
      mu[mf][r] = m_;
      rs[mf][r] = rsqrtf(v_ + 1e-5f);
    }

  // ---- gates: normalize + activate -> LDS bf16 [32][2048] (overwrites A-tile) ----
  unsigned short* gates = reinterpret_cast<unsigned short*>(smem);
  const int gsel = nw >> 1;                // 0:i 1:f 2:g 3:o
  #pragma unroll
  for (int t = 0; t < 16; t++) {
    int c = colb + t * 16;
    float gv  = gamma[c];                  // transient loads
    float btv = beta[c];
    #pragma unroll
    for (int mf = 0; mf < 2; mf++)
      #pragma unroll
      for (int r = 0; r < 4; r++) {
        float zn = (acc[mf][t][r] - mu[mf][r]) * rs[mf][r] * gv + btv;
        float a;
        if (gsel == 2) a = tanhf(zn);
        else           a = 1.0f / (1.0f + __expf(-zn));
        int lrow = mf * 16 + (lane >> 4) * 4 + r;
        gates[lrow * 2048 + c] = f2bf(a);
      }
  }
  __syncthreads();

  // ---- cell update: 32 rows x 256 col-pairs, 16 iters of 512 threads ----
  #pragma unroll
  for (int j = 0; j < 16; j++) {
    int idx  = tid + j * 512;              // 0..8191
    int col  = (idx & 255) * 2;
    int lr   = idx >> 8;                   // 0..31
    int grow = rowbase + lr;
    float2 iv = bf2x2(gates + lr * 2048 + col);
    float2 fv = bf2x2(gates + lr * 2048 + 512 + col);
    float2 gg = bf2x2(gates + lr * 2048 + 1024 + col);
    float2 ov = bf2x2(gates + lr * 2048 + 1536 + col);
    float2 cp = *reinterpret_cast<const float2*>(cprev + (size_t)grow * 512 + col);
    float2 cn, hn;
    cn.x = fv.x * cp.x + iv.x * gg.x;
    cn.y = fv.y * cp.y + iv.y * gg.y;
    hn.x = ov.x * tanhf(cn.x);
    hn.y = ov.y * tanhf(cn.y);
    *reinterpret_cast<float2*>(out + (size_t)grow * 512 + col) = hn;
    *reinterpret_cast<float2*>(out + (size_t)NROWS * 512 + (size_t)grow * 512 + col) = cn;
  }
}

extern "C" void kernel_launch(void* const* d_in, const int* in_sizes, int n_in,
                              void* d_out, int out_size, void* d_ws, size_t ws_size,
                              hipStream_t stream) {
  (void)in_sizes; (void)n_in; (void)out_size; (void)ws_size;
  const float* x     = (const float*)d_in[0];
  const float* h     = (const float*)d_in[1];
  const float* c     = (const float*)d_in[2];
  const float* W     = (const float*)d_in[3];
  const float* b     = (const float*)d_in[4];
  const float* gamma = (const float*)d_in[5];
  const float* beta  = (const float*)d_in[6];
  float* out = (float*)d_out;
  unsigned short* Wp = (unsigned short*)d_ws;   // 3 MB packed bf16 W

  hipFuncSetAttribute((const void*)lstm_main,
                      hipFuncAttributeMaxDynamicSharedMemorySize, LDS_BYTES);

  hipLaunchKernelGGL(pack_w_kernel, dim3(768), dim3(256), 0, stream, W, Wp);
  hipLaunchKernelGGL(lstm_main, dim3(1024), dim3(512), LDS_BYTES, stream,
                     x, h, c, Wp, b, gamma, beta, out);
}

// Round 6
// 496.421 us; speedup vs baseline: 3.3621x; 1.2286x over previous
//
#include <hip/hip_runtime.h>

typedef __attribute__((ext_vector_type(4))) float f32x4;
typedef __attribute__((ext_vector_type(8))) __bf16 bf16x8;

#define NROWS   32768
#define KDIM    768
#define NDIM    2048
#define HDIM    512
// [0,128K) gates bf16[32][2048]  (A-tile 48K unions at [0,48K), dead after K-loop)
// [128K,130K) reduce scratch [32 rows][8 waves][2]
#define LDS_BYTES 133120

__device__ __forceinline__ unsigned short f2bf(float f) {
  unsigned int u = __builtin_bit_cast(unsigned int, f);
  u += 0x7fffu + ((u >> 16) & 1u);          // RNE
  return (unsigned short)(u >> 16);
}
__device__ __forceinline__ float2 bf2x2(const unsigned short* p) {
  unsigned int u = *reinterpret_cast<const unsigned int*>(p);
  float2 r;
  r.x = __builtin_bit_cast(float, u << 16);
  r.y = __builtin_bit_cast(float, u & 0xffff0000u);
  return r;
}

// ---- kernel 0: pack W fp32 [768][2048] -> bf16 fragment-order buffer ----
// element index = ((nb*24 + kb)*64 + lane)*8 + j  holds  W[kb*32 + (lane>>4)*8 + j][nb*16 + (lane&15)]
__global__ void pack_w_kernel(const float* __restrict__ W, unsigned short* __restrict__ Wp) {
  int t = blockIdx.x * 256 + threadIdx.x;      // 0 .. 196607
  int lane = t & 63;
  int frag = t >> 6;                           // nb*24 + kb
  int kb = frag % 24;
  int nb = frag / 24;
  int krow = kb * 32 + (lane >> 4) * 8;
  int col  = nb * 16 + (lane & 15);
  unsigned int v[8];
  #pragma unroll
  for (int j = 0; j < 8; j++)
    v[j] = f2bf(W[(size_t)(krow + j) * NDIM + col]);
  uint4 pk;
  pk.x = v[0] | (v[1] << 16);
  pk.y = v[2] | (v[3] << 16);
  pk.z = v[4] | (v[5] << 16);
  pk.w = v[6] | (v[7] << 16);
  *reinterpret_cast<uint4*>(Wp + (size_t)t * 8) = pk;
}

// ---- main fused kernel: GEMM + LayerNorm + gates + cell update ----
// 512 threads = 8 waves = 2 waves/SIMD -> 256-reg/wave budget (no spill).
// Block: 32 rows x 2048 cols. Wave: 32 rows x 256 cols (nw = wid).
__global__ __launch_bounds__(512, 2) void lstm_main(
    const float* __restrict__ x, const float* __restrict__ hprev,
    const float* __restrict__ cprev, const unsigned short* __restrict__ Wp,
    const float* __restrict__ bias, const float* __restrict__ gamma,
    const float* __restrict__ beta, float* __restrict__ out)
{
  extern __shared__ char smem[];
  float* red = reinterpret_cast<float*>(smem + 131072);   // [32 rows][8 waves][2]

  const int tid  = threadIdx.x;
  const int lane = tid & 63;
  const int nw   = tid >> 6;               // 0..7  (256-col slice)
  const int rowbase = blockIdx.x * 32;

  // ---- stage A = [x | h_prev] rows into LDS as bf16, XOR-swizzled ----
  // 32 rows x 768 cols, 8-elem chunks: 96/row, 3072 total, 6/thread
  #pragma unroll
  for (int i = 0; i < 6; i++) {
    int chunk = tid + i * 512;
    int r  = chunk / 96;
    int kc = chunk % 96;
    int k  = kc * 8;
    int grow = rowbase + r;
    const float* src = (k < 256) ? (x + (size_t)grow * 256 + k)
                                 : (hprev + (size_t)grow * 512 + (k - 256));
    float4 lo = *reinterpret_cast<const float4*>(src);
    float4 hi = *reinterpret_cast<const float4*>(src + 4);
    uint4 pk;
    pk.x = (unsigned)f2bf(lo.x) | ((unsigned)f2bf(lo.y) << 16);
    pk.y = (unsigned)f2bf(lo.z) | ((unsigned)f2bf(lo.w) << 16);
    pk.z = (unsigned)f2bf(hi.x) | ((unsigned)f2bf(hi.y) << 16);
    pk.w = (unsigned)f2bf(hi.z) | ((unsigned)f2bf(hi.w) << 16);
    int boff = r * 1536 + ((k * 2) ^ ((r & 7) << 4));
    *reinterpret_cast<uint4*>(smem + boff) = pk;
  }
  __syncthreads();

  // ---- K-loop: acc[2 mfrag][16 nfrag]; mf0 = rows 0-15, mf1 = rows 16-31 ----
  f32x4 acc[2][16];
  #pragma unroll
  for (int mf = 0; mf < 2; mf++)
    #pragma unroll
    for (int t = 0; t < 16; t++)
      acc[mf][t] = (f32x4){0.f, 0.f, 0.f, 0.f};

  const int arow0 = lane & 15;
  const int kgrp  = lane >> 4;
  const int xorm  = (arow0 & 7) << 4;

  for (int kb = 0; kb < 24; kb++) {
    int cb   = kb * 64 + kgrp * 16;
    int off0 = arow0 * 1536 + (cb ^ xorm);
    bf16x8 a0 = *reinterpret_cast<const bf16x8*>(smem + off0);
    bf16x8 a1 = *reinterpret_cast<const bf16x8*>(smem + off0 + 16 * 1536);
    // batch all 16 B-fragment loads (one L2 round-trip exposed per kb, not 16)
    const bf16x8* wpv = reinterpret_cast<const bf16x8*>(
        Wp + ((size_t)(nw * 384 + kb) * 64 + lane) * 8);
    bf16x8 bt[16];
    #pragma unroll
    for (int t = 0; t < 16; t++)
      bt[t] = wpv[(size_t)t * 1536];       // stride 24*64*8 shorts = 24576 B
    __builtin_amdgcn_s_setprio(1);
    #pragma unroll
    for (int t = 0; t < 16; t++) {
      acc[0][t] = __builtin_amdgcn_mfma_f32_16x16x32_bf16(a0, bt[t], acc[0][t], 0, 0, 0);
      acc[1][t] = __builtin_amdgcn_mfma_f32_16x16x32_bf16(a1, bt[t], acc[1][t], 0, 0, 0);
    }
    __builtin_amdgcn_s_setprio(0);
  }

  // ---- bias + LN stats (col = nw*256 + t*16 + (lane&15), row = mf*16+(lane>>4)*4+r) ----
  const int colb = nw * 256 + (lane & 15);
  float s[2][4], q[2][4];
  #pragma unroll
  for (int mf = 0; mf < 2; mf++)
    #pragma unroll
    for (int r = 0; r < 4; r++) { s[mf][r] = 0.f; q[mf][r] = 0.f; }
  #pragma unroll
  for (int t = 0; t < 16; t++) {
    float bv = bias[colb + t * 16];          // transient load (keeps VGPR pressure low)
    #pragma unroll
    for (int mf = 0; mf < 2; mf++)
      #pragma unroll
      for (int r = 0; r < 4; r++) {
        float z = acc[mf][t][r] + bv;
        acc[mf][t][r] = z;
        s[mf][r] += z;
        q[mf][r] += z * z;
      }
  }
  #pragma unroll
  for (int m = 1; m <= 8; m <<= 1) {
    #pragma unroll
    for (int mf = 0; mf < 2; mf++)
      #pragma unroll
      for (int r = 0; r < 4; r++) {
        s[mf][r] += __shfl_xor(s[mf][r], m);
        q[mf][r] += __shfl_xor(q[mf][r], m);
      }
  }
  if ((lane & 15) == 0) {
    int g = lane >> 4;
    #pragma unroll
    for (int mf = 0; mf < 2; mf++)
      #pragma unroll
      for (int r = 0; r < 4; r++) {
        int row32 = mf * 16 + g * 4 + r;
        red[(row32 * 8 + nw) * 2 + 0] = s[mf][r];
        red[(row32 * 8 + nw) * 2 + 1] = q[mf][r];
      }
  }
  __syncthreads();
  float mu[2][4], rs[2][4];
  #pragma unroll
  for (int mf = 0; mf < 2; mf++)
    #pragma unroll
    for (int r = 0; r < 4; r++) {
      int row32 = mf * 16 + (lane >> 4) * 4 + r;
      float ts = 0.f, tq = 0.f;
      #pragma unroll
      for (int w = 0; w < 8; w++) {
        ts += red[(row32 * 8 + w) * 2 + 0];
        tq += red[(row32 * 8 + w) * 2 + 1];
      }
      float m_ = ts * (1.0f / 2048.0f);
      float v_ = tq * (1.0f / 2048.0f) - m_ * m_;
      mu[mf][r] = m_;
      rs[mf][r] = rsqrtf(v_ + 1e-5f);
    }

  // ---- gates: normalize + activate -> LDS bf16 [32][2048] (overwrites A-tile) ----
  unsigned short* gates = reinterpret_cast<unsigned short*>(smem);
  const int gsel = nw >> 1;                // 0:i 1:f 2:g 3:o
  #pragma unroll
  for (int t = 0; t < 16; t++) {
    int c = colb + t * 16;
    float gv  = gamma[c];                  // transient loads
    float btv = beta[c];
    #pragma unroll
    for (int mf = 0; mf < 2; mf++)
      #pragma unroll
      for (int r = 0; r < 4; r++) {
        float zn = (acc[mf][t][r] - mu[mf][r]) * rs[mf][r] * gv + btv;
        float a;
        if (gsel == 2) a = tanhf(zn);
        else           a = 1.0f / (1.0f + __expf(-zn));
        int lrow = mf * 16 + (lane >> 4) * 4 + r;
        gates[lrow * 2048 + c] = f2bf(a);
      }
  }
  __syncthreads();

  // ---- cell update: 32 rows x 256 col-pairs, 16 iters of 512 threads ----
  #pragma unroll
  for (int j = 0; j < 16; j++) {
    int idx  = tid + j * 512;              // 0..8191
    int col  = (idx & 255) * 2;
    int lr   = idx >> 8;                   // 0..31
    int grow = rowbase + lr;
    float2 iv = bf2x2(gates + lr * 2048 + col);
    float2 fv = bf2x2(gates + lr * 2048 + 512 + col);
    float2 gg = bf2x2(gates + lr * 2048 + 1024 + col);
    float2 ov = bf2x2(gates + lr * 2048 + 1536 + col);
    float2 cp = *reinterpret_cast<const float2*>(cprev + (size_t)grow * 512 + col);
    float2 cn, hn;
    cn.x = fv.x * cp.x + iv.x * gg.x;
    cn.y = fv.y * cp.y + iv.y * gg.y;
    hn.x = ov.x * tanhf(cn.x);
    hn.y = ov.y * tanhf(cn.y);
    *reinterpret_cast<float2*>(out + (size_t)grow * 512 + col) = hn;
    *reinterpret_cast<float2*>(out + (size_t)NROWS * 512 + (size_t)grow * 512 + col) = cn;
  }
}

extern "C" void kernel_launch(void* const* d_in, const int* in_sizes, int n_in,
                              void* d_out, int out_size, void* d_ws, size_t ws_size,
                              hipStream_t stream) {
  (void)in_sizes; (void)n_in; (void)out_size; (void)ws_size;
  const float* x     = (const float*)d_in[0];
  const float* h     = (const float*)d_in[1];
  const float* c     = (const float*)d_in[2];
  const float* W     = (const float*)d_in[3];
  const float* b     = (const float*)d_in[4];
  const float* gamma = (const float*)d_in[5];
  const float* beta  = (const float*)d_in[6];
  float* out = (float*)d_out;
  unsigned short* Wp = (unsigned short*)d_ws;   // 3 MB packed bf16 W

  hipFuncSetAttribute((const void*)lstm_main,
                      hipFuncAttributeMaxDynamicSharedMemorySize, LDS_BYTES);

  hipLaunchKernelGGL(pack_w_kernel, dim3(768), dim3(256), 0, stream, W, Wp);
  hipLaunchKernelGGL(lstm_main, dim3(1024), dim3(512), LDS_BYTES, stream,
                     x, h, c, Wp, b, gamma, beta, out);
}